// Round 1
// baseline (970.548 us; speedup 1.0000x reference)
//
#include <hip/hip_runtime.h>
#include <math.h>

// Problem constants
#define PTOT 36864          // Bsz*Hs*Ws = 16*48*48
#define DIM 768
#define NCOLS 640           // packed projection columns (613 used, padded to 640)
#define IMG 2304            // 48*48

__device__ __forceinline__ float sigmoidf_(float v) { return 1.f / (1.f + __expf(-v)); }
__device__ __forceinline__ float siluf_(float v)    { return v   / (1.f + __expf(-v)); }

// ---------------------------------------------------------------------------
// Pack all projection weights into W_all[768][640] and fused bias_all[640].
// Column map: [0,256) B (silu, +b_B+B_bias) | [256,512) C (silu, +b_C+C_bias)
//             [512,576) alpha (sigmoid)     | [576,608) theta (none)
//             [608,612) X (silu)            | 612 gamma (sigmoid) | pad 0
// ---------------------------------------------------------------------------
__global__ void pack_kernel(
    const float* __restrict__ W_B, const float* __restrict__ W_C,
    const float* __restrict__ W_dec, const float* __restrict__ W_th,
    const float* __restrict__ W_X, const float* __restrict__ W_lam,
    const float* __restrict__ b_B, const float* __restrict__ b_C,
    const float* __restrict__ b_dec, const float* __restrict__ b_th,
    const float* __restrict__ b_X, const float* __restrict__ b_lam,
    const float* __restrict__ B_bias, const float* __restrict__ C_bias,
    float* __restrict__ W_all, float* __restrict__ bias_all) {
  int idx = blockIdx.x * 256 + threadIdx.x;
  if (idx < DIM * NCOLS) {
    int k = idx / NCOLS, c = idx % NCOLS;
    float v;
    if      (c < 256) v = W_B[k * 256 + c];
    else if (c < 512) v = W_C[k * 256 + (c - 256)];
    else if (c < 576) v = W_dec[k * 64 + (c - 512)];
    else if (c < 608) v = W_th[k * 32 + (c - 576)];
    else if (c < 612) v = W_X[k * 4 + (c - 608)];
    else if (c == 612) v = W_lam[k];
    else v = 0.f;
    W_all[idx] = v;
  }
  if (idx < NCOLS) {
    int c = idx;
    float v;
    if      (c < 256) v = b_B[c] + B_bias[c];
    else if (c < 512) v = b_C[c - 256] + C_bias[c - 256];
    else if (c < 576) v = b_dec[c - 512];
    else if (c < 608) v = b_th[c - 576];
    else if (c < 612) v = b_X[c - 608];
    else if (c == 612) v = b_lam[0];
    else v = 0.f;
    bias_all[c] = v;
  }
}

// ---------------------------------------------------------------------------
// GEMM A: projT[c][p] = act_c( sum_k x[p][k] * W_all[k][c] + bias_all[c] )
// Tile 128p x 128c, K-tile 32, 256 threads, 8x8 microtile.
// xs is stored K-major (transposed on LDS write) so the compute reads are
// float4; stride 132 keeps 16B alignment + spreads banks.
// ---------------------------------------------------------------------------
__global__ __launch_bounds__(256) void gemm_proj(
    const float* __restrict__ x, const float* __restrict__ Wall,
    const float* __restrict__ biasall, float* __restrict__ projT) {
  __shared__ float xs[32 * 132];
  __shared__ float wsh[32 * 132];
  const int tid = threadIdx.x;
  const int p0 = blockIdx.x * 128;
  const int c0 = blockIdx.y * 128;
  const int tc = tid & 15, tp = tid >> 4;

  float acc[8][8];
#pragma unroll
  for (int i = 0; i < 8; ++i)
#pragma unroll
    for (int j = 0; j < 8; ++j) acc[i][j] = 0.f;

  for (int k0 = 0; k0 < DIM; k0 += 32) {
    // load x tile [128p][32k], store transposed K-major
#pragma unroll
    for (int l = 0; l < 4; ++l) {
      int q = tid + 256 * l;           // 0..1023
      int row = q >> 3, kq = q & 7;    // row: p idx, kq: k-quad
      const float4 v = *(const float4*)&x[(size_t)(p0 + row) * DIM + k0 + 4 * kq];
      xs[(4 * kq + 0) * 132 + row] = v.x;
      xs[(4 * kq + 1) * 132 + row] = v.y;
      xs[(4 * kq + 2) * 132 + row] = v.z;
      xs[(4 * kq + 3) * 132 + row] = v.w;
    }
    // load W tile [32k][128c]
#pragma unroll
    for (int l = 0; l < 4; ++l) {
      int q = tid + 256 * l;
      int row = q >> 5, cq = q & 31;
      const float4 v = *(const float4*)&Wall[(size_t)(k0 + row) * NCOLS + c0 + 4 * cq];
      *(float4*)&wsh[row * 132 + 4 * cq] = v;
    }
    __syncthreads();
#pragma unroll
    for (int kk = 0; kk < 32; ++kk) {
      float4 a0 = *(float4*)&xs[kk * 132 + tp * 8];
      float4 a1 = *(float4*)&xs[kk * 132 + tp * 8 + 4];
      float4 b0 = *(float4*)&wsh[kk * 132 + tc * 4];
      float4 b1 = *(float4*)&wsh[kk * 132 + 64 + tc * 4];
      float av[8] = {a0.x, a0.y, a0.z, a0.w, a1.x, a1.y, a1.z, a1.w};
      float bv[8] = {b0.x, b0.y, b0.z, b0.w, b1.x, b1.y, b1.z, b1.w};
#pragma unroll
      for (int i = 0; i < 8; ++i)
#pragma unroll
        for (int j = 0; j < 8; ++j) acc[i][j] += av[i] * bv[j];
    }
    __syncthreads();
  }

  // epilogue: per-column activation, store transposed (p contiguous)
#pragma unroll
  for (int j = 0; j < 8; ++j) {
    int c = c0 + ((j < 4) ? (tc * 4 + j) : (64 + tc * 4 + (j - 4)));
    float bia = biasall[c];
#pragma unroll
    for (int h = 0; h < 2; ++h) {
      float4 v;
      float* vp = &v.x;
#pragma unroll
      for (int t = 0; t < 4; ++t) {
        float z = acc[h * 4 + t][j] + bia;
        if (c < 512) z = siluf_(z);
        else if (c < 576) z = sigmoidf_(z);
        else if (c >= 608 && c < 612) z = siluf_(z);
        else if (c == 612) z = sigmoidf_(z);
        vp[t] = z;
      }
      *(float4*)&projT[(size_t)c * PTOT + p0 + tp * 8 + h * 4] = v;
    }
  }
}

// ---------------------------------------------------------------------------
// Iteration kernel: one block per (n-pair, r, batch). Whole 48x48 image for
// the 2 channels lives in LDS (interleaved float2). All 12 iterations fused.
// cos/sin(k*theta) by incremental complex rotation.
// Writes HgT[r*64+n][p] (K-major for final GEMM).
// ---------------------------------------------------------------------------
__global__ __launch_bounds__(256) void iter_kernel(
    const float* __restrict__ projT, const float* __restrict__ conv_w,
    const float* __restrict__ conv_b, float* __restrict__ HgT) {
  const int n2 = blockIdx.x;   // channel pair 0..31
  const int r  = blockIdx.y;   // 0..3
  const int b  = blockIdx.z;   // 0..15
  const int n0 = 2 * n2, n1 = n0 + 1;
  const int tid = threadIdx.x;
  const int pbase = b * IMG;

  __shared__ float HS[IMG * 2];   // [pixel][channel] interleaved

  float w0[9], w1[9];
#pragma unroll
  for (int t = 0; t < 9; ++t) {
    w0[t] = conv_w[t * 64 + n0];
    w1[t] = conv_w[t * 64 + n1];
  }
  const float cvb0 = conv_b[n0], cvb1 = conv_b[n1];

  const float* rowB0 = projT + (size_t)(n0 * 4 + r) * PTOT + pbase;
  const float* rowB1 = projT + (size_t)(n1 * 4 + r) * PTOT + pbase;
  const float* rowC0 = projT + (size_t)(256 + n0 * 4 + r) * PTOT + pbase;
  const float* rowC1 = projT + (size_t)(256 + n1 * 4 + r) * PTOT + pbase;
  const float* rowA0 = projT + (size_t)(512 + n0) * PTOT + pbase;
  const float* rowA1 = projT + (size_t)(512 + n1) * PTOT + pbase;
  const float* rowTh = projT + (size_t)(576 + n2) * PTOT + pbase;
  const float* rowXv = projT + (size_t)(608 + r) * PTOT + pbase;
  const float* rowGm = projT + (size_t)612 * PTOT + pbase;

  float b0v[9], b1v[9], al0v[9], al1v[9], xvv[9], gmv[9];
  float cbv[9], sbv[9], cv[9], sv[9], p0v[9], p1v[9];

#pragma unroll
  for (int j = 0; j < 9; ++j) {
    int i = tid + 256 * j;
    b0v[j] = rowB0[i];  b1v[j] = rowB1[i];
    al0v[j] = rowA0[i]; al1v[j] = rowA1[i];
    xvv[j] = rowXv[i];  gmv[j] = rowGm[i];
    float th = rowTh[i];
    float s, c;
    __sincosf(th, &s, &c);
    cbv[j] = c; sbv[j] = s;   // rotation step (theta)
    cv[j] = c;  sv[j] = s;    // current angle = theta*(it+1), starts at theta
    p0v[j] = 0.f; p1v[j] = 0.f;
    HS[2 * i] = 0.f; HS[2 * i + 1] = 0.f;
  }
  __syncthreads();

  for (int it = 0; it < 12; ++it) {
    float hn0[9], hn1[9];
#pragma unroll
    for (int j = 0; j < 9; ++j) {
      int i = tid + 256 * j;
      int h = i / 48, w = i - h * 48;
      float a0 = cvb0, a1 = cvb1;
#pragma unroll
      for (int dy = 0; dy < 3; ++dy) {
        int hh = h + dy - 1;
        if (hh < 0 || hh >= 48) continue;
#pragma unroll
        for (int dx = 0; dx < 3; ++dx) {
          int ww = w + dx - 1;
          if (ww < 0 || ww >= 48) continue;
          float2 v = *(const float2*)&HS[2 * (hh * 48 + ww)];
          a0 += v.x * w0[dy * 3 + dx];
          a1 += v.y * w1[dy * 3 + dx];
        }
      }
      hn0[j] = a0; hn1[j] = a1;
    }
    __syncthreads();
#pragma unroll
    for (int j = 0; j < 9; ++j) {
      int i = tid + 256 * j;
      float inj0 = (b0v[j] * cv[j] - b1v[j] * sv[j]) * xvv[j];
      float inj1 = (b0v[j] * sv[j] + b1v[j] * cv[j]) * xvv[j];
      float h0, h1;
      if (it == 0) {
        h0 = al0v[j] * hn0[j] + inj0;
        h1 = al1v[j] * hn1[j] + inj1;
      } else {
        float g = gmv[j];
        h0 = al0v[j] * hn0[j] + (1.f - g) * al0v[j] * p0v[j] + g * inj0;
        h1 = al1v[j] * hn1[j] + (1.f - g) * al1v[j] * p1v[j] + g * inj1;
      }
      p0v[j] = inj0; p1v[j] = inj1;
      if (it < 11) {  // after it=11, cv/sv hold cos/sin(12*theta) for C_rot
        float cn = cv[j] * cbv[j] - sv[j] * sbv[j];
        float sn = cv[j] * sbv[j] + sv[j] * cbv[j];
        cv[j] = cn; sv[j] = sn;
      }
      float2 hw; hw.x = h0; hw.y = h1;
      *(float2*)&HS[2 * i] = hw;
    }
    __syncthreads();
  }

  // Hg = rope(C, 12*theta) * Hst, stored K-major for the output GEMM
  float* outRow0 = HgT + (size_t)(r * 64 + n0) * PTOT + pbase;
  float* outRow1 = HgT + (size_t)(r * 64 + n1) * PTOT + pbase;
#pragma unroll
  for (int j = 0; j < 9; ++j) {
    int i = tid + 256 * j;
    float c0 = rowC0[i], c1 = rowC1[i];
    float cr0 = c0 * cv[j] - c1 * sv[j];
    float cr1 = c0 * sv[j] + c1 * cv[j];
    float2 hv = *(const float2*)&HS[2 * i];
    outRow0[i] = cr0 * hv.x;
    outRow1[i] = cr1 * hv.y;
  }
}

// ---------------------------------------------------------------------------
// GEMM C: out[p][j] = silu( sum_k HgT[k][p] * W_out[k][j] + b_out[j] )
// Same tiling as GEMM A; A operand is already K-major so no transpose needed.
// ---------------------------------------------------------------------------
__global__ __launch_bounds__(256) void gemm_out_k(
    const float* __restrict__ HgT, const float* __restrict__ W_out,
    const float* __restrict__ b_out, float* __restrict__ out) {
  __shared__ float as[32 * 132];
  __shared__ float wsh[32 * 132];
  const int tid = threadIdx.x;
  const int p0 = blockIdx.x * 128;
  const int j0 = blockIdx.y * 128;
  const int tc = tid & 15, tp = tid >> 4;

  float acc[8][8];
#pragma unroll
  for (int i = 0; i < 8; ++i)
#pragma unroll
    for (int j = 0; j < 8; ++j) acc[i][j] = 0.f;

  for (int k0 = 0; k0 < 256; k0 += 32) {
#pragma unroll
    for (int l = 0; l < 4; ++l) {
      int q = tid + 256 * l;
      int row = q >> 5, pq = q & 31;
      *(float4*)&as[row * 132 + 4 * pq] =
          *(const float4*)&HgT[(size_t)(k0 + row) * PTOT + p0 + 4 * pq];
    }
#pragma unroll
    for (int l = 0; l < 4; ++l) {
      int q = tid + 256 * l;
      int row = q >> 5, cq = q & 31;
      *(float4*)&wsh[row * 132 + 4 * cq] =
          *(const float4*)&W_out[(size_t)(k0 + row) * DIM + j0 + 4 * cq];
    }
    __syncthreads();
#pragma unroll
    for (int kk = 0; kk < 32; ++kk) {
      float4 a0 = *(float4*)&as[kk * 132 + tp * 8];
      float4 a1 = *(float4*)&as[kk * 132 + tp * 8 + 4];
      float4 b0 = *(float4*)&wsh[kk * 132 + tc * 4];
      float4 b1 = *(float4*)&wsh[kk * 132 + 64 + tc * 4];
      float av[8] = {a0.x, a0.y, a0.z, a0.w, a1.x, a1.y, a1.z, a1.w};
      float bv[8] = {b0.x, b0.y, b0.z, b0.w, b1.x, b1.y, b1.z, b1.w};
#pragma unroll
      for (int i = 0; i < 8; ++i)
#pragma unroll
        for (int j = 0; j < 8; ++j) acc[i][j] += av[i] * bv[j];
    }
    __syncthreads();
  }

#pragma unroll
  for (int i = 0; i < 8; ++i) {
    int p = p0 + tp * 8 + i;
    size_t rowoff = (size_t)p * DIM;
    float4 v0, v1;
    float* v0p = &v0.x;
    float* v1p = &v1.x;
#pragma unroll
    for (int t = 0; t < 4; ++t) {
      v0p[t] = siluf_(acc[i][t] + b_out[j0 + tc * 4 + t]);
      v1p[t] = siluf_(acc[i][4 + t] + b_out[j0 + 64 + tc * 4 + t]);
    }
    *(float4*)&out[rowoff + j0 + tc * 4] = v0;
    *(float4*)&out[rowoff + j0 + 64 + tc * 4] = v1;
  }
}

// ---------------------------------------------------------------------------
extern "C" void kernel_launch(void* const* d_in, const int* in_sizes, int n_in,
                              void* d_out, int out_size, void* d_ws, size_t ws_size,
                              hipStream_t stream) {
  const float* x      = (const float*)d_in[0];
  const float* W_B    = (const float*)d_in[1];
  const float* b_B    = (const float*)d_in[2];
  const float* W_C    = (const float*)d_in[3];
  const float* b_C    = (const float*)d_in[4];
  const float* W_X    = (const float*)d_in[5];
  const float* b_X    = (const float*)d_in[6];
  const float* W_dec  = (const float*)d_in[7];
  const float* b_dec  = (const float*)d_in[8];
  const float* W_th   = (const float*)d_in[9];
  const float* b_th   = (const float*)d_in[10];
  const float* W_lam  = (const float*)d_in[11];
  const float* b_lam  = (const float*)d_in[12];
  const float* B_bias = (const float*)d_in[13];
  const float* C_bias = (const float*)d_in[14];
  const float* conv_w = (const float*)d_in[15];
  const float* conv_b = (const float*)d_in[16];
  const float* W_out  = (const float*)d_in[17];
  const float* b_out  = (const float*)d_in[18];
  float* out = (float*)d_out;

  float* wsf      = (float*)d_ws;
  float* W_all    = wsf;                                  // 768*640
  float* bias_all = W_all + (size_t)DIM * NCOLS;          // 640
  float* projT    = bias_all + NCOLS;                     // 640*36864
  float* HgT      = projT + (size_t)NCOLS * PTOT;         // 256*36864

  pack_kernel<<<(DIM * NCOLS + 255) / 256, 256, 0, stream>>>(
      W_B, W_C, W_dec, W_th, W_X, W_lam,
      b_B, b_C, b_dec, b_th, b_X, b_lam, B_bias, C_bias,
      W_all, bias_all);

  gemm_proj<<<dim3(PTOT / 128, NCOLS / 128), 256, 0, stream>>>(
      x, W_all, bias_all, projT);

  iter_kernel<<<dim3(32, 4, 16), 256, 0, stream>>>(
      projT, conv_w, conv_b, HgT);

  gemm_out_k<<<dim3(PTOT / 128, DIM / 128), 256, 0, stream>>>(
      HgT, W_out, b_out, out);
}

// Round 2
// 648.617 us; speedup vs baseline: 1.4963x; 1.4963x over previous
//
#include <hip/hip_runtime.h>
#include <math.h>

// Problem constants
#define PTOT 36864          // Bsz*Hs*Ws = 16*48*48
#define DIM 768
#define NCOLS 640           // packed projection columns (613 used, padded)
#define IMG 2304            // 48*48
#define PROJ_ROWS 616       // projT rows actually allocated (612 used)

typedef unsigned short ushort_t;
typedef unsigned int uint_t;
typedef __attribute__((ext_vector_type(8))) short bfx8;
typedef __attribute__((ext_vector_type(4))) float f32x4;

#define MFMA_BF16(a, b, c) __builtin_amdgcn_mfma_f32_16x16x32_bf16((a), (b), (c), 0, 0, 0)

__device__ __forceinline__ float sigmoidf_(float v) { return 1.f / (1.f + __expf(-v)); }
__device__ __forceinline__ float siluf_(float v)    { return v   / (1.f + __expf(-v)); }

__device__ __forceinline__ ushort_t bf16_rne(float f) {
  union { float f; uint_t u; } v; v.f = f;
  uint_t r = v.u + 0x7fffu + ((v.u >> 16) & 1u);
  return (ushort_t)(r >> 16);
}
__device__ __forceinline__ float bf16_tof(ushort_t h) {
  union { uint_t u; float f; } v; v.u = ((uint_t)h) << 16; return v.f;
}
// split 8 floats into bf16 hi + bf16 lo, packed as uint4 each
__device__ __forceinline__ void split8(const float* f, uint4& hi, uint4& lo) {
  ushort_t h[8], l[8];
#pragma unroll
  for (int i = 0; i < 8; ++i) {
    h[i] = bf16_rne(f[i]);
    l[i] = bf16_rne(f[i] - bf16_tof(h[i]));
  }
  hi.x = (uint_t)h[0] | ((uint_t)h[1] << 16);
  hi.y = (uint_t)h[2] | ((uint_t)h[3] << 16);
  hi.z = (uint_t)h[4] | ((uint_t)h[5] << 16);
  hi.w = (uint_t)h[6] | ((uint_t)h[7] << 16);
  lo.x = (uint_t)l[0] | ((uint_t)l[1] << 16);
  lo.y = (uint_t)l[2] | ((uint_t)l[3] << 16);
  lo.z = (uint_t)l[4] | ((uint_t)l[5] << 16);
  lo.w = (uint_t)l[6] | ((uint_t)l[7] << 16);
}

// ---------------------------------------------------------------------------
// pack: build split-bf16 transposed weights + fused bias.
//  WhiT/WloT  [c][k]  c in [0,640): col map as round-1
//  WoThi/WoTlo [j][k] j in [0,768), k in [0,256)  (W_out transposed)
// ---------------------------------------------------------------------------
__global__ void pack_kernel(
    const float* __restrict__ W_B, const float* __restrict__ W_C,
    const float* __restrict__ W_dec, const float* __restrict__ W_th,
    const float* __restrict__ W_X, const float* __restrict__ W_lam,
    const float* __restrict__ b_B, const float* __restrict__ b_C,
    const float* __restrict__ b_dec, const float* __restrict__ b_th,
    const float* __restrict__ b_X, const float* __restrict__ b_lam,
    const float* __restrict__ B_bias, const float* __restrict__ C_bias,
    const float* __restrict__ W_out,
    ushort_t* __restrict__ WhiT, ushort_t* __restrict__ WloT,
    ushort_t* __restrict__ WoThi, ushort_t* __restrict__ WoTlo,
    float* __restrict__ bias_all) {
  int idx = blockIdx.x * 256 + threadIdx.x;
  const int NW = NCOLS * DIM;          // 491520
  const int NWO = DIM * 256;           // 196608
  if (idx < NW) {
    int c = idx / DIM, k = idx - c * DIM;
    float v;
    if      (c < 256) v = W_B[k * 256 + c];
    else if (c < 512) v = W_C[k * 256 + (c - 256)];
    else if (c < 576) v = W_dec[k * 64 + (c - 512)];
    else if (c < 608) v = W_th[k * 32 + (c - 576)];
    else if (c < 612) v = W_X[k * 4 + (c - 608)];
    else if (c == 612) v = W_lam[k];
    else v = 0.f;
    ushort_t h = bf16_rne(v);
    WhiT[idx] = h;
    WloT[idx] = bf16_rne(v - bf16_tof(h));
  } else if (idx < NW + NWO) {
    int t = idx - NW;
    int j = t / 256, k = t - j * 256;
    float v = W_out[k * DIM + j];
    ushort_t h = bf16_rne(v);
    WoThi[t] = h;
    WoTlo[t] = bf16_rne(v - bf16_tof(h));
  }
  if (idx < NCOLS) {
    int c = idx;
    float v;
    if      (c < 256) v = b_B[c] + B_bias[c];
    else if (c < 512) v = b_C[c - 256] + C_bias[c - 256];
    else if (c < 576) v = b_dec[c - 512];
    else if (c < 608) v = b_th[c - 576];
    else if (c < 612) v = b_X[c - 608];
    else if (c == 612) v = b_lam[0];
    else v = 0.f;
    bias_all[c] = v;
  }
}

// ---------------------------------------------------------------------------
// GEMM A (split-bf16 MFMA): projT[c][p] = act_c( sum_k W[k][c]*x[p][k] + bias )
// A-operand = W rows (c), B-operand = x cols (p). 128x128 tile, 4 waves
// (2x2 of 64x64), K-step 32. LDS layout [kgroup g][row 128][8 bf16].
// ---------------------------------------------------------------------------
__global__ __launch_bounds__(256) void gemm_proj_mfma(
    const float* __restrict__ x, const ushort_t* __restrict__ WhiT,
    const ushort_t* __restrict__ WloT, const float* __restrict__ biasall,
    float* __restrict__ projT) {
  __shared__ ushort_t As_hi[4096], As_lo[4096];  // W tile
  __shared__ ushort_t Bs_hi[4096], Bs_lo[4096];  // x tile
  const int tid = threadIdx.x;
  // XCD-bijective swizzle; c-block fastest so the 5 c-blocks sharing a
  // p-tile of x are consecutive (L2-co-resident) within an XCD.
  int lin = blockIdx.y * 5 + blockIdx.x;          // 0..1439
  int id2 = (lin & 7) * 180 + (lin >> 3);
  const int cblk = id2 % 5, pblk = id2 / 5;
  const int c0 = cblk * 128, p0 = pblk * 128;
  const int lane = tid & 63, wv = tid >> 6;
  const int wr = wv >> 1, wc = wv & 1;
  const int lk = lane >> 4, lm = lane & 15;

  f32x4 acc[4][4];
#pragma unroll
  for (int i = 0; i < 4; ++i)
#pragma unroll
    for (int j = 0; j < 4; ++j) acc[i][j] = (f32x4)0.f;

  for (int k0 = 0; k0 < DIM; k0 += 32) {
    // stage W (already split in global)
#pragma unroll
    for (int s = 0; s < 2; ++s) {
      int u = tid + 256 * s;
      int c = u >> 2, g = u & 3;
      size_t goff = (size_t)(c0 + c) * DIM + k0 + g * 8;
      *(uint4*)&As_hi[(g * 128 + c) * 8] = *(const uint4*)&WhiT[goff];
      *(uint4*)&As_lo[(g * 128 + c) * 8] = *(const uint4*)&WloT[goff];
    }
    // stage x (convert f32 -> hi/lo during staging)
#pragma unroll
    for (int s = 0; s < 2; ++s) {
      int u = tid + 256 * s;
      int p = u >> 2, g = u & 3;
      const float* xp = &x[(size_t)(p0 + p) * DIM + k0 + g * 8];
      float f[8];
      *(float4*)&f[0] = *(const float4*)xp;
      *(float4*)&f[4] = *(const float4*)(xp + 4);
      uint4 hv, lv;
      split8(f, hv, lv);
      *(uint4*)&Bs_hi[(g * 128 + p) * 8] = hv;
      *(uint4*)&Bs_lo[(g * 128 + p) * 8] = lv;
    }
    __syncthreads();
    bfx8 ah[4], al[4], bh[4], bl[4];
#pragma unroll
    for (int f = 0; f < 4; ++f) {
      int ai = (lk * 128 + wr * 64 + f * 16 + lm) * 8;
      ah[f] = *(const bfx8*)&As_hi[ai];
      al[f] = *(const bfx8*)&As_lo[ai];
      int bi = (lk * 128 + wc * 64 + f * 16 + lm) * 8;
      bh[f] = *(const bfx8*)&Bs_hi[bi];
      bl[f] = *(const bfx8*)&Bs_lo[bi];
    }
#pragma unroll
    for (int i = 0; i < 4; ++i)
#pragma unroll
      for (int j = 0; j < 4; ++j) {
        acc[i][j] = MFMA_BF16(ah[i], bh[j], acc[i][j]);
        acc[i][j] = MFMA_BF16(al[i], bh[j], acc[i][j]);
        acc[i][j] = MFMA_BF16(ah[i], bl[j], acc[i][j]);
      }
    __syncthreads();
  }

  // epilogue: c = row, p = col (lane-contiguous -> coalesced dword stores)
#pragma unroll
  for (int i = 0; i < 4; ++i) {
#pragma unroll
    for (int r = 0; r < 4; ++r) {
      int c = c0 + wr * 64 + i * 16 + lk * 4 + r;
      if (c >= PROJ_ROWS) continue;
      float bia = biasall[c];
      bool do_silu = (c < 512) || (c >= 608 && c < 612);
      bool do_sig  = (c >= 512 && c < 576) || (c == 612);
#pragma unroll
      for (int j = 0; j < 4; ++j) {
        float z = acc[i][j][r] + bia;
        if (do_silu) z = siluf_(z);
        else if (do_sig) z = sigmoidf_(z);
        projT[(size_t)c * PTOT + p0 + wc * 64 + j * 16 + lm] = z;
      }
    }
  }
}

// ---------------------------------------------------------------------------
// Iteration kernel (unchanged math): one block per (n-pair, r, batch), all 12
// iterations fused in LDS. Now writes Hg as split-bf16 in [p][k] layout
// (k = r*64 + n, contiguous) for the output GEMM's vectorized staging.
// ---------------------------------------------------------------------------
__global__ __launch_bounds__(256) void iter_kernel(
    const float* __restrict__ projT, const float* __restrict__ conv_w,
    const float* __restrict__ conv_b, ushort_t* __restrict__ Hhi,
    ushort_t* __restrict__ Hlo) {
  const int n2 = blockIdx.x;   // channel pair 0..31
  const int r  = blockIdx.y;   // 0..3
  const int b  = blockIdx.z;   // 0..15
  const int n0 = 2 * n2, n1 = n0 + 1;
  const int tid = threadIdx.x;
  const int pbase = b * IMG;

  __shared__ float HS[IMG * 2];

  float w0[9], w1[9];
#pragma unroll
  for (int t = 0; t < 9; ++t) {
    w0[t] = conv_w[t * 64 + n0];
    w1[t] = conv_w[t * 64 + n1];
  }
  const float cvb0 = conv_b[n0], cvb1 = conv_b[n1];

  const float* rowB0 = projT + (size_t)(n0 * 4 + r) * PTOT + pbase;
  const float* rowB1 = projT + (size_t)(n1 * 4 + r) * PTOT + pbase;
  const float* rowC0 = projT + (size_t)(256 + n0 * 4 + r) * PTOT + pbase;
  const float* rowC1 = projT + (size_t)(256 + n1 * 4 + r) * PTOT + pbase;
  const float* rowA0 = projT + (size_t)(512 + n0) * PTOT + pbase;
  const float* rowA1 = projT + (size_t)(512 + n1) * PTOT + pbase;
  const float* rowTh = projT + (size_t)(576 + n2) * PTOT + pbase;
  const float* rowXv = projT + (size_t)(608 + r) * PTOT + pbase;
  const float* rowGm = projT + (size_t)612 * PTOT + pbase;

  float b0v[9], b1v[9], al0v[9], al1v[9], xvv[9], gmv[9];
  float cbv[9], sbv[9], cv[9], sv[9], p0v[9], p1v[9];

#pragma unroll
  for (int j = 0; j < 9; ++j) {
    int i = tid + 256 * j;
    b0v[j] = rowB0[i];  b1v[j] = rowB1[i];
    al0v[j] = rowA0[i]; al1v[j] = rowA1[i];
    xvv[j] = rowXv[i];  gmv[j] = rowGm[i];
    float th = rowTh[i];
    float s, c;
    __sincosf(th, &s, &c);
    cbv[j] = c; sbv[j] = s;
    cv[j] = c;  sv[j] = s;
    p0v[j] = 0.f; p1v[j] = 0.f;
    HS[2 * i] = 0.f; HS[2 * i + 1] = 0.f;
  }
  __syncthreads();

  for (int it = 0; it < 12; ++it) {
    float hn0[9], hn1[9];
#pragma unroll
    for (int j = 0; j < 9; ++j) {
      int i = tid + 256 * j;
      int h = i / 48, w = i - h * 48;
      float a0 = cvb0, a1 = cvb1;
#pragma unroll
      for (int dy = 0; dy < 3; ++dy) {
        int hh = h + dy - 1;
        if (hh < 0 || hh >= 48) continue;
#pragma unroll
        for (int dx = 0; dx < 3; ++dx) {
          int ww = w + dx - 1;
          if (ww < 0 || ww >= 48) continue;
          float2 v = *(const float2*)&HS[2 * (hh * 48 + ww)];
          a0 += v.x * w0[dy * 3 + dx];
          a1 += v.y * w1[dy * 3 + dx];
        }
      }
      hn0[j] = a0; hn1[j] = a1;
    }
    __syncthreads();
#pragma unroll
    for (int j = 0; j < 9; ++j) {
      int i = tid + 256 * j;
      float inj0 = (b0v[j] * cv[j] - b1v[j] * sv[j]) * xvv[j];
      float inj1 = (b0v[j] * sv[j] + b1v[j] * cv[j]) * xvv[j];
      float h0, h1;
      if (it == 0) {
        h0 = al0v[j] * hn0[j] + inj0;
        h1 = al1v[j] * hn1[j] + inj1;
      } else {
        float g = gmv[j];
        h0 = al0v[j] * hn0[j] + (1.f - g) * al0v[j] * p0v[j] + g * inj0;
        h1 = al1v[j] * hn1[j] + (1.f - g) * al1v[j] * p1v[j] + g * inj1;
      }
      p0v[j] = inj0; p1v[j] = inj1;
      if (it < 11) {
        float cn = cv[j] * cbv[j] - sv[j] * sbv[j];
        float sn = cv[j] * sbv[j] + sv[j] * cbv[j];
        cv[j] = cn; sv[j] = sn;
      }
      float2 hw; hw.x = h0; hw.y = h1;
      *(float2*)&HS[2 * i] = hw;
    }
    __syncthreads();
  }

  // Hg = rope(C, 12*theta) * Hst -> split bf16, [p][k] layout, k = r*64+n
#pragma unroll
  for (int j = 0; j < 9; ++j) {
    int i = tid + 256 * j;
    float c0 = rowC0[i], c1 = rowC1[i];
    float cr0 = c0 * cv[j] - c1 * sv[j];
    float cr1 = c0 * sv[j] + c1 * cv[j];
    float2 hv = *(const float2*)&HS[2 * i];
    float v0 = cr0 * hv.x, v1 = cr1 * hv.y;
    ushort_t h0 = bf16_rne(v0);
    ushort_t l0 = bf16_rne(v0 - bf16_tof(h0));
    ushort_t h1 = bf16_rne(v1);
    ushort_t l1 = bf16_rne(v1 - bf16_tof(h1));
    size_t off = (size_t)(pbase + i) * 256 + r * 64 + n0;
    *(uint_t*)&Hhi[off] = (uint_t)h0 | ((uint_t)h1 << 16);
    *(uint_t*)&Hlo[off] = (uint_t)l0 | ((uint_t)l1 << 16);
  }
}

// ---------------------------------------------------------------------------
// GEMM C (split-bf16 MFMA): out[p][j] = silu( sum_k Hg[p][k]*W_out[k][j] + b )
// A-operand = Hg rows (p), B-operand = W_out^T cols (j). K = 256.
// ---------------------------------------------------------------------------
__global__ __launch_bounds__(256) void gemm_out_mfma(
    const ushort_t* __restrict__ Hhi, const ushort_t* __restrict__ Hlo,
    const ushort_t* __restrict__ WoThi, const ushort_t* __restrict__ WoTlo,
    const float* __restrict__ b_out, float* __restrict__ out) {
  __shared__ ushort_t As_hi[4096], As_lo[4096];  // Hg tile
  __shared__ ushort_t Bs_hi[4096], Bs_lo[4096];  // W_out^T tile
  const int tid = threadIdx.x;
  int lin = blockIdx.y * 6 + blockIdx.x;          // 0..1727
  int id2 = (lin & 7) * 216 + (lin >> 3);
  const int jblk = id2 % 6, pblk = id2 / 6;
  const int j0 = jblk * 128, p0 = pblk * 128;
  const int lane = tid & 63, wv = tid >> 6;
  const int wr = wv >> 1, wc = wv & 1;
  const int lk = lane >> 4, lm = lane & 15;

  f32x4 acc[4][4];
#pragma unroll
  for (int i = 0; i < 4; ++i)
#pragma unroll
    for (int j = 0; j < 4; ++j) acc[i][j] = (f32x4)0.f;

  for (int k0 = 0; k0 < 256; k0 += 32) {
#pragma unroll
    for (int s = 0; s < 2; ++s) {
      int u = tid + 256 * s;
      int p = u >> 2, g = u & 3;
      size_t goff = (size_t)(p0 + p) * 256 + k0 + g * 8;
      *(uint4*)&As_hi[(g * 128 + p) * 8] = *(const uint4*)&Hhi[goff];
      *(uint4*)&As_lo[(g * 128 + p) * 8] = *(const uint4*)&Hlo[goff];
    }
#pragma unroll
    for (int s = 0; s < 2; ++s) {
      int u = tid + 256 * s;
      int j = u >> 2, g = u & 3;
      size_t goff = (size_t)(j0 + j) * 256 + k0 + g * 8;
      *(uint4*)&Bs_hi[(g * 128 + j) * 8] = *(const uint4*)&WoThi[goff];
      *(uint4*)&Bs_lo[(g * 128 + j) * 8] = *(const uint4*)&WoTlo[goff];
    }
    __syncthreads();
    bfx8 ah[4], al[4], bh[4], bl[4];
#pragma unroll
    for (int f = 0; f < 4; ++f) {
      int ai = (lk * 128 + wr * 64 + f * 16 + lm) * 8;
      ah[f] = *(const bfx8*)&As_hi[ai];
      al[f] = *(const bfx8*)&As_lo[ai];
      int bi = (lk * 128 + wc * 64 + f * 16 + lm) * 8;
      bh[f] = *(const bfx8*)&Bs_hi[bi];
      bl[f] = *(const bfx8*)&Bs_lo[bi];
    }
#pragma unroll
    for (int i = 0; i < 4; ++i)
#pragma unroll
      for (int j = 0; j < 4; ++j) {
        acc[i][j] = MFMA_BF16(ah[i], bh[j], acc[i][j]);
        acc[i][j] = MFMA_BF16(al[i], bh[j], acc[i][j]);
        acc[i][j] = MFMA_BF16(ah[i], bl[j], acc[i][j]);
      }
    __syncthreads();
  }

  float bo[4];
#pragma unroll
  for (int jj = 0; jj < 4; ++jj) bo[jj] = b_out[j0 + wc * 64 + jj * 16 + lm];
#pragma unroll
  for (int i = 0; i < 4; ++i) {
#pragma unroll
    for (int r = 0; r < 4; ++r) {
      int p = p0 + wr * 64 + i * 16 + lk * 4 + r;
      size_t rowoff = (size_t)p * DIM;
#pragma unroll
      for (int jj = 0; jj < 4; ++jj) {
        out[rowoff + j0 + wc * 64 + jj * 16 + lm] =
            siluf_(acc[i][jj][r] + bo[jj]);
      }
    }
  }
}

// ---------------------------------------------------------------------------
extern "C" void kernel_launch(void* const* d_in, const int* in_sizes, int n_in,
                              void* d_out, int out_size, void* d_ws, size_t ws_size,
                              hipStream_t stream) {
  const float* x      = (const float*)d_in[0];
  const float* W_B    = (const float*)d_in[1];
  const float* b_B    = (const float*)d_in[2];
  const float* W_C    = (const float*)d_in[3];
  const float* b_C    = (const float*)d_in[4];
  const float* W_X    = (const float*)d_in[5];
  const float* b_X    = (const float*)d_in[6];
  const float* W_dec  = (const float*)d_in[7];
  const float* b_dec  = (const float*)d_in[8];
  const float* W_th   = (const float*)d_in[9];
  const float* b_th   = (const float*)d_in[10];
  const float* W_lam  = (const float*)d_in[11];
  const float* b_lam  = (const float*)d_in[12];
  const float* B_bias = (const float*)d_in[13];
  const float* C_bias = (const float*)d_in[14];
  const float* conv_w = (const float*)d_in[15];
  const float* conv_b = (const float*)d_in[16];
  const float* W_out  = (const float*)d_in[17];
  const float* b_out  = (const float*)d_in[18];
  float* out = (float*)d_out;

  // workspace layout (total ~131.3 MB)
  ushort_t* WhiT  = (ushort_t*)d_ws;                      // 640*768
  ushort_t* WloT  = WhiT + (size_t)NCOLS * DIM;
  ushort_t* WoThi = WloT + (size_t)NCOLS * DIM;           // 768*256
  ushort_t* WoTlo = WoThi + (size_t)DIM * 256;
  float* bias_all = (float*)(WoTlo + (size_t)DIM * 256);  // 640
  float* projT    = bias_all + NCOLS;                     // 616*36864 f32
  ushort_t* Hhi   = (ushort_t*)(projT + (size_t)PROJ_ROWS * PTOT);  // 36864*256
  ushort_t* Hlo   = Hhi + (size_t)PTOT * 256;

  const int pack_elems = NCOLS * DIM + DIM * 256;
  pack_kernel<<<(pack_elems + 255) / 256, 256, 0, stream>>>(
      W_B, W_C, W_dec, W_th, W_X, W_lam,
      b_B, b_C, b_dec, b_th, b_X, b_lam, B_bias, C_bias, W_out,
      WhiT, WloT, WoThi, WoTlo, bias_all);

  gemm_proj_mfma<<<dim3(5, PTOT / 128), 256, 0, stream>>>(
      x, WhiT, WloT, bias_all, projT);

  iter_kernel<<<dim3(32, 4, 16), 256, 0, stream>>>(
      projT, conv_w, conv_b, Hhi, Hlo);

  gemm_out_mfma<<<dim3(6, PTOT / 128), 256, 0, stream>>>(
      Hhi, Hlo, WoThi, WoTlo, b_out, out);
}

// Round 3
// 432.524 us; speedup vs baseline: 2.2439x; 1.4996x over previous
//
#include <hip/hip_runtime.h>
#include <math.h>

// Problem constants
#define PTOT 36864          // Bsz*Hs*Ws = 16*48*48
#define DIM 768
#define NCOLS 640           // packed projection columns (613 used, padded)
#define IMG 2304            // 48*48
#define PROJ_ROWS 616       // projT rows actually allocated (612 used)

typedef unsigned short ushort_t;
typedef unsigned int uint_t;
typedef __attribute__((ext_vector_type(8))) short bfx8;
typedef __attribute__((ext_vector_type(4))) float f32x4;

#define MFMA_BF16(a, b, c) __builtin_amdgcn_mfma_f32_16x16x32_bf16((a), (b), (c), 0, 0, 0)

__device__ __forceinline__ float sigmoidf_(float v) { return 1.f / (1.f + __expf(-v)); }
__device__ __forceinline__ float siluf_(float v)    { return v   / (1.f + __expf(-v)); }
__device__ __forceinline__ float rfl(float v) {
  return __int_as_float(__builtin_amdgcn_readfirstlane(__float_as_int(v)));
}

__device__ __forceinline__ ushort_t bf16_rne(float f) {
  union { float f; uint_t u; } v; v.f = f;
  uint_t r = v.u + 0x7fffu + ((v.u >> 16) & 1u);
  return (ushort_t)(r >> 16);
}
__device__ __forceinline__ float bf16_tof(ushort_t h) {
  union { uint_t u; float f; } v; v.u = ((uint_t)h) << 16; return v.f;
}
// split 8 floats into bf16 hi + bf16 lo, packed as uint4 each
__device__ __forceinline__ void split8(const float* f, uint4& hi, uint4& lo) {
  ushort_t h[8], l[8];
#pragma unroll
  for (int i = 0; i < 8; ++i) {
    h[i] = bf16_rne(f[i]);
    l[i] = bf16_rne(f[i] - bf16_tof(h[i]));
  }
  hi.x = (uint_t)h[0] | ((uint_t)h[1] << 16);
  hi.y = (uint_t)h[2] | ((uint_t)h[3] << 16);
  hi.z = (uint_t)h[4] | ((uint_t)h[5] << 16);
  hi.w = (uint_t)h[6] | ((uint_t)h[7] << 16);
  lo.x = (uint_t)l[0] | ((uint_t)l[1] << 16);
  lo.y = (uint_t)l[2] | ((uint_t)l[3] << 16);
  lo.z = (uint_t)l[4] | ((uint_t)l[5] << 16);
  lo.w = (uint_t)l[6] | ((uint_t)l[7] << 16);
}

// ---------------------------------------------------------------------------
// pack: build split-bf16 transposed weights + fused bias.
// ---------------------------------------------------------------------------
__global__ void pack_kernel(
    const float* __restrict__ W_B, const float* __restrict__ W_C,
    const float* __restrict__ W_dec, const float* __restrict__ W_th,
    const float* __restrict__ W_X, const float* __restrict__ W_lam,
    const float* __restrict__ b_B, const float* __restrict__ b_C,
    const float* __restrict__ b_dec, const float* __restrict__ b_th,
    const float* __restrict__ b_X, const float* __restrict__ b_lam,
    const float* __restrict__ B_bias, const float* __restrict__ C_bias,
    const float* __restrict__ W_out,
    ushort_t* __restrict__ WhiT, ushort_t* __restrict__ WloT,
    ushort_t* __restrict__ WoThi, ushort_t* __restrict__ WoTlo,
    float* __restrict__ bias_all) {
  int idx = blockIdx.x * 256 + threadIdx.x;
  const int NW = NCOLS * DIM;          // 491520
  const int NWO = DIM * 256;           // 196608
  if (idx < NW) {
    int c = idx / DIM, k = idx - c * DIM;
    float v;
    if      (c < 256) v = W_B[k * 256 + c];
    else if (c < 512) v = W_C[k * 256 + (c - 256)];
    else if (c < 576) v = W_dec[k * 64 + (c - 512)];
    else if (c < 608) v = W_th[k * 32 + (c - 576)];
    else if (c < 612) v = W_X[k * 4 + (c - 608)];
    else if (c == 612) v = W_lam[k];
    else v = 0.f;
    ushort_t h = bf16_rne(v);
    WhiT[idx] = h;
    WloT[idx] = bf16_rne(v - bf16_tof(h));
  } else if (idx < NW + NWO) {
    int t = idx - NW;
    int j = t / 256, k = t - j * 256;
    float v = W_out[k * DIM + j];
    ushort_t h = bf16_rne(v);
    WoThi[t] = h;
    WoTlo[t] = bf16_rne(v - bf16_tof(h));
  }
  if (idx < NCOLS) {
    int c = idx;
    float v;
    if      (c < 256) v = b_B[c] + B_bias[c];
    else if (c < 512) v = b_C[c - 256] + C_bias[c - 256];
    else if (c < 576) v = b_dec[c - 512];
    else if (c < 608) v = b_th[c - 576];
    else if (c < 612) v = b_X[c - 608];
    else if (c == 612) v = b_lam[0];
    else v = 0.f;
    bias_all[c] = v;
  }
}

// ---------------------------------------------------------------------------
// GEMM A (split-bf16 MFMA): projT[c][p] = act_c( sum_k W[k][c]*x[p][k] + bias )
// ---------------------------------------------------------------------------
__global__ __launch_bounds__(256) void gemm_proj_mfma(
    const float* __restrict__ x, const ushort_t* __restrict__ WhiT,
    const ushort_t* __restrict__ WloT, const float* __restrict__ biasall,
    float* __restrict__ projT) {
  __shared__ ushort_t As_hi[4096], As_lo[4096];  // W tile
  __shared__ ushort_t Bs_hi[4096], Bs_lo[4096];  // x tile
  const int tid = threadIdx.x;
  int lin = blockIdx.y * 5 + blockIdx.x;          // 0..1439
  int id2 = (lin & 7) * 180 + (lin >> 3);
  const int cblk = id2 % 5, pblk = id2 / 5;
  const int c0 = cblk * 128, p0 = pblk * 128;
  const int lane = tid & 63, wv = tid >> 6;
  const int wr = wv >> 1, wc = wv & 1;
  const int lk = lane >> 4, lm = lane & 15;

  f32x4 acc[4][4];
#pragma unroll
  for (int i = 0; i < 4; ++i)
#pragma unroll
    for (int j = 0; j < 4; ++j) acc[i][j] = (f32x4)0.f;

  for (int k0 = 0; k0 < DIM; k0 += 32) {
#pragma unroll
    for (int s = 0; s < 2; ++s) {
      int u = tid + 256 * s;
      int c = u >> 2, g = u & 3;
      size_t goff = (size_t)(c0 + c) * DIM + k0 + g * 8;
      *(uint4*)&As_hi[(g * 128 + c) * 8] = *(const uint4*)&WhiT[goff];
      *(uint4*)&As_lo[(g * 128 + c) * 8] = *(const uint4*)&WloT[goff];
    }
#pragma unroll
    for (int s = 0; s < 2; ++s) {
      int u = tid + 256 * s;
      int p = u >> 2, g = u & 3;
      const float* xp = &x[(size_t)(p0 + p) * DIM + k0 + g * 8];
      float f[8];
      *(float4*)&f[0] = *(const float4*)xp;
      *(float4*)&f[4] = *(const float4*)(xp + 4);
      uint4 hv, lv;
      split8(f, hv, lv);
      *(uint4*)&Bs_hi[(g * 128 + p) * 8] = hv;
      *(uint4*)&Bs_lo[(g * 128 + p) * 8] = lv;
    }
    __syncthreads();
    bfx8 ah[4], al[4], bh[4], bl[4];
#pragma unroll
    for (int f = 0; f < 4; ++f) {
      int ai = (lk * 128 + wr * 64 + f * 16 + lm) * 8;
      ah[f] = *(const bfx8*)&As_hi[ai];
      al[f] = *(const bfx8*)&As_lo[ai];
      int bi = (lk * 128 + wc * 64 + f * 16 + lm) * 8;
      bh[f] = *(const bfx8*)&Bs_hi[bi];
      bl[f] = *(const bfx8*)&Bs_lo[bi];
    }
#pragma unroll
    for (int i = 0; i < 4; ++i)
#pragma unroll
      for (int j = 0; j < 4; ++j) {
        acc[i][j] = MFMA_BF16(ah[i], bh[j], acc[i][j]);
        acc[i][j] = MFMA_BF16(al[i], bh[j], acc[i][j]);
        acc[i][j] = MFMA_BF16(ah[i], bl[j], acc[i][j]);
      }
    __syncthreads();
  }

#pragma unroll
  for (int i = 0; i < 4; ++i) {
#pragma unroll
    for (int r = 0; r < 4; ++r) {
      int c = c0 + wr * 64 + i * 16 + lk * 4 + r;
      if (c >= PROJ_ROWS) continue;
      float bia = biasall[c];
      bool do_silu = (c < 512) || (c >= 608 && c < 612);
      bool do_sig  = (c >= 512 && c < 576) || (c == 612);
#pragma unroll
      for (int j = 0; j < 4; ++j) {
        float z = acc[i][j][r] + bia;
        if (do_silu) z = siluf_(z);
        else if (do_sig) z = sigmoidf_(z);
        projT[(size_t)c * PTOT + p0 + wc * 64 + j * 16 + lm] = z;
      }
    }
  }
}

// ---------------------------------------------------------------------------
// Iteration kernel v2: one block per (n-pair, r, batch). 12 iterations fused.
// Live state minimized: beta (= rope(B,theta*(i+1))*X) rotates in registers;
// prev-inj recovered by rotating beta backwards; C_rot angle from (cb,sb)^12.
// Double-buffered zero-padded 50x50 LDS image -> 1 barrier/iter, no edge
// branches, no values live across a barrier except the 7 invariant arrays.
// ---------------------------------------------------------------------------
__global__ __launch_bounds__(256) void iter_kernel(
    const float* __restrict__ projT, const float* __restrict__ conv_w,
    const float* __restrict__ conv_b, ushort_t* __restrict__ Hhi,
    ushort_t* __restrict__ Hlo) {
  const int n2 = blockIdx.x;   // channel pair 0..31
  const int r  = blockIdx.y;   // 0..3
  const int b  = blockIdx.z;   // 0..15
  const int n0 = 2 * n2, n1 = n0 + 1;
  const int tid = threadIdx.x;
  const int pbase = b * IMG;

  __shared__ float2 HS[2][2500];   // [buf][(h+1)*50 + (w+1)], zero halo

  // wave-uniform conv weights -> SGPRs
  float w0[9], w1[9];
#pragma unroll
  for (int t = 0; t < 9; ++t) {
    w0[t] = rfl(conv_w[t * 64 + n0]);
    w1[t] = rfl(conv_w[t * 64 + n1]);
  }
  const float cvb0 = rfl(conv_b[n0]), cvb1 = rfl(conv_b[n1]);

  // zero both buffers (5000 float2 = 2500 float4)
  {
    float4 zz = {0.f, 0.f, 0.f, 0.f};
    float4* z = (float4*)&HS[0][0];
#pragma unroll
    for (int u = 0; u < 10; ++u) {
      int q = tid + 256 * u;
      if (q < 2500) z[q] = zz;
    }
  }

  const float* rowB0 = projT + (size_t)(n0 * 4 + r) * PTOT + pbase;
  const float* rowB1 = projT + (size_t)(n1 * 4 + r) * PTOT + pbase;
  const float* rowC0 = projT + (size_t)(256 + n0 * 4 + r) * PTOT + pbase;
  const float* rowC1 = projT + (size_t)(256 + n1 * 4 + r) * PTOT + pbase;
  const float* rowA0 = projT + (size_t)(512 + n0) * PTOT + pbase;
  const float* rowA1 = projT + (size_t)(512 + n1) * PTOT + pbase;
  const float* rowTh = projT + (size_t)(576 + n2) * PTOT + pbase;
  const float* rowXv = projT + (size_t)(608 + r) * PTOT + pbase;
  const float* rowGm = projT + (size_t)612 * PTOT + pbase;

  float be0[9], be1[9], cb[9], sb[9], al0[9], al1[9], gmv[9];
#pragma unroll
  for (int j = 0; j < 9; ++j) {
    int i = tid + 256 * j;
    float s, c;
    __sincosf(rowTh[i], &s, &c);
    cb[j] = c; sb[j] = s;
    float B0 = rowB0[i], B1 = rowB1[i], X = rowXv[i];
    be0[j] = (B0 * c - B1 * s) * X;   // inj at angle theta (iteration 0)
    be1[j] = (B0 * s + B1 * c) * X;
    al0[j] = rowA0[i]; al1[j] = rowA1[i];
    gmv[j] = rowGm[i];
  }
  __syncthreads();

  int cur = 0;
  for (int it = 0; it < 12; ++it) {
#pragma unroll
    for (int j = 0; j < 9; ++j) {
      int i = tid + 256 * j;
      int h = i / 48, w = i - h * 48;
      int base = h * 50 + w;           // tap (dy,dx) at base + dy*50 + dx
      float a0 = cvb0, a1 = cvb1;
#pragma unroll
      for (int dy = 0; dy < 3; ++dy)
#pragma unroll
        for (int dx = 0; dx < 3; ++dx) {
          float2 v = HS[cur][base + dy * 50 + dx];
          a0 += v.x * w0[dy * 3 + dx];
          a1 += v.y * w1[dy * 3 + dx];
        }
      float h0, h1;
      if (it == 0) {
        h0 = al0[j] * a0 + be0[j];
        h1 = al1[j] * a1 + be1[j];
      } else {
        // prev inj = rot(beta, -theta)
        float p0 = be0[j] * cb[j] + be1[j] * sb[j];
        float p1 = be1[j] * cb[j] - be0[j] * sb[j];
        float g = gmv[j];
        h0 = al0[j] * (a0 + (1.f - g) * p0) + g * be0[j];
        h1 = al1[j] * (a1 + (1.f - g) * p1) + g * be1[j];
      }
      float2 hw; hw.x = h0; hw.y = h1;
      HS[cur ^ 1][base + 51] = hw;     // (h+1)*50 + (w+1)
      if (it < 11) {                   // advance beta by theta
        float nb0 = be0[j] * cb[j] - be1[j] * sb[j];
        float nb1 = be0[j] * sb[j] + be1[j] * cb[j];
        be0[j] = nb0; be1[j] = nb1;
      }
    }
    __syncthreads();
    cur ^= 1;
  }

  // Hg = rope(C, 12*theta) * Hst -> split bf16, [p][k] layout, k = r*64+n
#pragma unroll
  for (int j = 0; j < 9; ++j) {
    int i = tid + 256 * j;
    // (cb + i sb)^12 via complex squarings: z2, z4, z8, z12 = z8*z4
    float c2 = cb[j] * cb[j] - sb[j] * sb[j], s2 = 2.f * cb[j] * sb[j];
    float c4 = c2 * c2 - s2 * s2,             s4 = 2.f * c2 * s2;
    float c8 = c4 * c4 - s4 * s4,             s8 = 2.f * c4 * s4;
    float c12 = c8 * c4 - s8 * s4,            s12 = c8 * s4 + s8 * c4;
    float C0 = rowC0[i], C1 = rowC1[i];
    float cr0 = C0 * c12 - C1 * s12;
    float cr1 = C0 * s12 + C1 * c12;
    int h = i / 48, w = i - h * 48;
    float2 hv = HS[cur][h * 50 + w + 51];
    float v0 = cr0 * hv.x, v1 = cr1 * hv.y;
    ushort_t h0 = bf16_rne(v0);
    ushort_t l0 = bf16_rne(v0 - bf16_tof(h0));
    ushort_t h1 = bf16_rne(v1);
    ushort_t l1 = bf16_rne(v1 - bf16_tof(h1));
    size_t off = (size_t)(pbase + i) * 256 + r * 64 + n0;
    *(uint_t*)&Hhi[off] = (uint_t)h0 | ((uint_t)h1 << 16);
    *(uint_t*)&Hlo[off] = (uint_t)l0 | ((uint_t)l1 << 16);
  }
}

// ---------------------------------------------------------------------------
// GEMM C (split-bf16 MFMA): out[p][j] = silu( sum_k Hg[p][k]*W_out[k][j] + b )
// ---------------------------------------------------------------------------
__global__ __launch_bounds__(256) void gemm_out_mfma(
    const ushort_t* __restrict__ Hhi, const ushort_t* __restrict__ Hlo,
    const ushort_t* __restrict__ WoThi, const ushort_t* __restrict__ WoTlo,
    const float* __restrict__ b_out, float* __restrict__ out) {
  __shared__ ushort_t As_hi[4096], As_lo[4096];  // Hg tile
  __shared__ ushort_t Bs_hi[4096], Bs_lo[4096];  // W_out^T tile
  const int tid = threadIdx.x;
  int lin = blockIdx.y * 6 + blockIdx.x;          // 0..1727
  int id2 = (lin & 7) * 216 + (lin >> 3);
  const int jblk = id2 % 6, pblk = id2 / 6;
  const int j0 = jblk * 128, p0 = pblk * 128;
  const int lane = tid & 63, wv = tid >> 6;
  const int wr = wv >> 1, wc = wv & 1;
  const int lk = lane >> 4, lm = lane & 15;

  f32x4 acc[4][4];
#pragma unroll
  for (int i = 0; i < 4; ++i)
#pragma unroll
    for (int j = 0; j < 4; ++j) acc[i][j] = (f32x4)0.f;

  for (int k0 = 0; k0 < 256; k0 += 32) {
#pragma unroll
    for (int s = 0; s < 2; ++s) {
      int u = tid + 256 * s;
      int p = u >> 2, g = u & 3;
      size_t goff = (size_t)(p0 + p) * 256 + k0 + g * 8;
      *(uint4*)&As_hi[(g * 128 + p) * 8] = *(const uint4*)&Hhi[goff];
      *(uint4*)&As_lo[(g * 128 + p) * 8] = *(const uint4*)&Hlo[goff];
    }
#pragma unroll
    for (int s = 0; s < 2; ++s) {
      int u = tid + 256 * s;
      int j = u >> 2, g = u & 3;
      size_t goff = (size_t)(j0 + j) * 256 + k0 + g * 8;
      *(uint4*)&Bs_hi[(g * 128 + j) * 8] = *(const uint4*)&WoThi[goff];
      *(uint4*)&Bs_lo[(g * 128 + j) * 8] = *(const uint4*)&WoTlo[goff];
    }
    __syncthreads();
    bfx8 ah[4], al[4], bh[4], bl[4];
#pragma unroll
    for (int f = 0; f < 4; ++f) {
      int ai = (lk * 128 + wr * 64 + f * 16 + lm) * 8;
      ah[f] = *(const bfx8*)&As_hi[ai];
      al[f] = *(const bfx8*)&As_lo[ai];
      int bi = (lk * 128 + wc * 64 + f * 16 + lm) * 8;
      bh[f] = *(const bfx8*)&Bs_hi[bi];
      bl[f] = *(const bfx8*)&Bs_lo[bi];
    }
#pragma unroll
    for (int i = 0; i < 4; ++i)
#pragma unroll
      for (int j = 0; j < 4; ++j) {
        acc[i][j] = MFMA_BF16(ah[i], bh[j], acc[i][j]);
        acc[i][j] = MFMA_BF16(al[i], bh[j], acc[i][j]);
        acc[i][j] = MFMA_BF16(ah[i], bl[j], acc[i][j]);
      }
    __syncthreads();
  }

  float bo[4];
#pragma unroll
  for (int jj = 0; jj < 4; ++jj) bo[jj] = b_out[j0 + wc * 64 + jj * 16 + lm];
#pragma unroll
  for (int i = 0; i < 4; ++i) {
#pragma unroll
    for (int r = 0; r < 4; ++r) {
      int p = p0 + wr * 64 + i * 16 + lk * 4 + r;
      size_t rowoff = (size_t)p * DIM;
#pragma unroll
      for (int jj = 0; jj < 4; ++jj) {
        out[rowoff + j0 + wc * 64 + jj * 16 + lm] =
            siluf_(acc[i][jj][r] + bo[jj]);
      }
    }
  }
}

// ---------------------------------------------------------------------------
extern "C" void kernel_launch(void* const* d_in, const int* in_sizes, int n_in,
                              void* d_out, int out_size, void* d_ws, size_t ws_size,
                              hipStream_t stream) {
  const float* x      = (const float*)d_in[0];
  const float* W_B    = (const float*)d_in[1];
  const float* b_B    = (const float*)d_in[2];
  const float* W_C    = (const float*)d_in[3];
  const float* b_C    = (const float*)d_in[4];
  const float* W_X    = (const float*)d_in[5];
  const float* b_X    = (const float*)d_in[6];
  const float* W_dec  = (const float*)d_in[7];
  const float* b_dec  = (const float*)d_in[8];
  const float* W_th   = (const float*)d_in[9];
  const float* b_th   = (const float*)d_in[10];
  const float* W_lam  = (const float*)d_in[11];
  const float* b_lam  = (const float*)d_in[12];
  const float* B_bias = (const float*)d_in[13];
  const float* C_bias = (const float*)d_in[14];
  const float* conv_w = (const float*)d_in[15];
  const float* conv_b = (const float*)d_in[16];
  const float* W_out  = (const float*)d_in[17];
  const float* b_out  = (const float*)d_in[18];
  float* out = (float*)d_out;

  // workspace layout (total ~131.3 MB)
  ushort_t* WhiT  = (ushort_t*)d_ws;                      // 640*768
  ushort_t* WloT  = WhiT + (size_t)NCOLS * DIM;
  ushort_t* WoThi = WloT + (size_t)NCOLS * DIM;           // 768*256
  ushort_t* WoTlo = WoThi + (size_t)DIM * 256;
  float* bias_all = (float*)(WoTlo + (size_t)DIM * 256);  // 640
  float* projT    = bias_all + NCOLS;                     // 616*36864 f32
  ushort_t* Hhi   = (ushort_t*)(projT + (size_t)PROJ_ROWS * PTOT);  // 36864*256
  ushort_t* Hlo   = Hhi + (size_t)PTOT * 256;

  const int pack_elems = NCOLS * DIM + DIM * 256;
  pack_kernel<<<(pack_elems + 255) / 256, 256, 0, stream>>>(
      W_B, W_C, W_dec, W_th, W_X, W_lam,
      b_B, b_C, b_dec, b_th, b_X, b_lam, B_bias, C_bias, W_out,
      WhiT, WloT, WoThi, WoTlo, bias_all);

  gemm_proj_mfma<<<dim3(5, PTOT / 128), 256, 0, stream>>>(
      x, WhiT, WloT, bias_all, projT);

  iter_kernel<<<dim3(32, 4, 16), 256, 0, stream>>>(
      projT, conv_w, conv_b, Hhi, Hlo);

  gemm_out_mfma<<<dim3(6, PTOT / 128), 256, 0, stream>>>(
      Hhi, Hlo, WoThi, WoTlo, b_out, out);
}

// Round 4
// 323.512 us; speedup vs baseline: 3.0000x; 1.3370x over previous
//
#include <hip/hip_runtime.h>
#include <math.h>

// Problem constants
#define PTOT 36864          // Bsz*Hs*Ws = 16*48*48
#define DIM 768
#define NCOLS 640           // packed projection columns (613 used, padded)
#define IMG 2304            // 48*48
#define PROJ_ROWS 616       // projT rows actually allocated (612 used)

typedef unsigned short ushort_t;
typedef unsigned int uint_t;
typedef __attribute__((ext_vector_type(8))) short bfx8;
typedef __attribute__((ext_vector_type(4))) float f32x4;

// padded LDS g-stride for GEMM tiles: 2144 B == 24 banks mod 32 -> staging
// writes are exactly 2-way (free); 1024 (2048 B == bank 0) was 4-way.
#define GSTR 1072

#define MFMA_BF16(a, b, c) __builtin_amdgcn_mfma_f32_16x16x32_bf16((a), (b), (c), 0, 0, 0)

__device__ __forceinline__ float sigmoidf_(float v) { return 1.f / (1.f + __expf(-v)); }
__device__ __forceinline__ float siluf_(float v)    { return v   / (1.f + __expf(-v)); }
__device__ __forceinline__ float rfl(float v) {
  return __int_as_float(__builtin_amdgcn_readfirstlane(__float_as_int(v)));
}

__device__ __forceinline__ ushort_t bf16_rne(float f) {
  union { float f; uint_t u; } v; v.f = f;
  uint_t r = v.u + 0x7fffu + ((v.u >> 16) & 1u);
  return (ushort_t)(r >> 16);
}
__device__ __forceinline__ float bf16_tof(ushort_t h) {
  union { uint_t u; float f; } v; v.u = ((uint_t)h) << 16; return v.f;
}
__device__ __forceinline__ void split8(const float* f, uint4& hi, uint4& lo) {
  ushort_t h[8], l[8];
#pragma unroll
  for (int i = 0; i < 8; ++i) {
    h[i] = bf16_rne(f[i]);
    l[i] = bf16_rne(f[i] - bf16_tof(h[i]));
  }
  hi.x = (uint_t)h[0] | ((uint_t)h[1] << 16);
  hi.y = (uint_t)h[2] | ((uint_t)h[3] << 16);
  hi.z = (uint_t)h[4] | ((uint_t)h[5] << 16);
  hi.w = (uint_t)h[6] | ((uint_t)h[7] << 16);
  lo.x = (uint_t)l[0] | ((uint_t)l[1] << 16);
  lo.y = (uint_t)l[2] | ((uint_t)l[3] << 16);
  lo.z = (uint_t)l[4] | ((uint_t)l[5] << 16);
  lo.w = (uint_t)l[6] | ((uint_t)l[7] << 16);
}

// ---------------------------------------------------------------------------
// pack: build split-bf16 transposed weights + fused bias.
// ---------------------------------------------------------------------------
__global__ void pack_kernel(
    const float* __restrict__ W_B, const float* __restrict__ W_C,
    const float* __restrict__ W_dec, const float* __restrict__ W_th,
    const float* __restrict__ W_X, const float* __restrict__ W_lam,
    const float* __restrict__ b_B, const float* __restrict__ b_C,
    const float* __restrict__ b_dec, const float* __restrict__ b_th,
    const float* __restrict__ b_X, const float* __restrict__ b_lam,
    const float* __restrict__ B_bias, const float* __restrict__ C_bias,
    const float* __restrict__ W_out,
    ushort_t* __restrict__ WhiT, ushort_t* __restrict__ WloT,
    ushort_t* __restrict__ WoThi, ushort_t* __restrict__ WoTlo,
    float* __restrict__ bias_all) {
  int idx = blockIdx.x * 256 + threadIdx.x;
  const int NW = NCOLS * DIM;          // 491520
  const int NWO = DIM * 256;           // 196608
  if (idx < NW) {
    int c = idx / DIM, k = idx - c * DIM;
    float v;
    if      (c < 256) v = W_B[k * 256 + c];
    else if (c < 512) v = W_C[k * 256 + (c - 256)];
    else if (c < 576) v = W_dec[k * 64 + (c - 512)];
    else if (c < 608) v = W_th[k * 32 + (c - 576)];
    else if (c < 612) v = W_X[k * 4 + (c - 608)];
    else if (c == 612) v = W_lam[k];
    else v = 0.f;
    ushort_t h = bf16_rne(v);
    WhiT[idx] = h;
    WloT[idx] = bf16_rne(v - bf16_tof(h));
  } else if (idx < NW + NWO) {
    int t = idx - NW;
    int j = t / 256, k = t - j * 256;
    float v = W_out[k * DIM + j];
    ushort_t h = bf16_rne(v);
    WoThi[t] = h;
    WoTlo[t] = bf16_rne(v - bf16_tof(h));
  }
  if (idx < NCOLS) {
    int c = idx;
    float v;
    if      (c < 256) v = b_B[c] + B_bias[c];
    else if (c < 512) v = b_C[c - 256] + C_bias[c - 256];
    else if (c < 576) v = b_dec[c - 512];
    else if (c < 608) v = b_th[c - 576];
    else if (c < 612) v = b_X[c - 608];
    else if (c == 612) v = b_lam[0];
    else v = 0.f;
    bias_all[c] = v;
  }
}

// ---------------------------------------------------------------------------
// GEMM A (split-bf16 MFMA): projT[c][p] = act_c( sum_k W[k][c]*x[p][k] + bias )
// ---------------------------------------------------------------------------
__global__ __launch_bounds__(256) void gemm_proj_mfma(
    const float* __restrict__ x, const ushort_t* __restrict__ WhiT,
    const ushort_t* __restrict__ WloT, const float* __restrict__ biasall,
    float* __restrict__ projT) {
  __shared__ ushort_t As_hi[4 * GSTR], As_lo[4 * GSTR];  // W tile
  __shared__ ushort_t Bs_hi[4 * GSTR], Bs_lo[4 * GSTR];  // x tile
  const int tid = threadIdx.x;
  int lin = blockIdx.y * 5 + blockIdx.x;          // 0..1439
  int id2 = (lin & 7) * 180 + (lin >> 3);
  const int cblk = id2 % 5, pblk = id2 / 5;
  const int c0 = cblk * 128, p0 = pblk * 128;
  const int lane = tid & 63, wv = tid >> 6;
  const int wr = wv >> 1, wc = wv & 1;
  const int lk = lane >> 4, lm = lane & 15;

  f32x4 acc[4][4];
#pragma unroll
  for (int i = 0; i < 4; ++i)
#pragma unroll
    for (int j = 0; j < 4; ++j) acc[i][j] = (f32x4)0.f;

  for (int k0 = 0; k0 < DIM; k0 += 32) {
#pragma unroll
    for (int s = 0; s < 2; ++s) {
      int u = tid + 256 * s;
      int c = u >> 2, g = u & 3;
      size_t goff = (size_t)(c0 + c) * DIM + k0 + g * 8;
      *(uint4*)&As_hi[g * GSTR + c * 8] = *(const uint4*)&WhiT[goff];
      *(uint4*)&As_lo[g * GSTR + c * 8] = *(const uint4*)&WloT[goff];
    }
#pragma unroll
    for (int s = 0; s < 2; ++s) {
      int u = tid + 256 * s;
      int p = u >> 2, g = u & 3;
      const float* xp = &x[(size_t)(p0 + p) * DIM + k0 + g * 8];
      float f[8];
      *(float4*)&f[0] = *(const float4*)xp;
      *(float4*)&f[4] = *(const float4*)(xp + 4);
      uint4 hv, lv;
      split8(f, hv, lv);
      *(uint4*)&Bs_hi[g * GSTR + p * 8] = hv;
      *(uint4*)&Bs_lo[g * GSTR + p * 8] = lv;
    }
    __syncthreads();
    bfx8 ah[4], al[4], bh[4], bl[4];
#pragma unroll
    for (int f = 0; f < 4; ++f) {
      int ai = lk * GSTR + (wr * 64 + f * 16 + lm) * 8;
      ah[f] = *(const bfx8*)&As_hi[ai];
      al[f] = *(const bfx8*)&As_lo[ai];
      int bi = lk * GSTR + (wc * 64 + f * 16 + lm) * 8;
      bh[f] = *(const bfx8*)&Bs_hi[bi];
      bl[f] = *(const bfx8*)&Bs_lo[bi];
    }
#pragma unroll
    for (int i = 0; i < 4; ++i)
#pragma unroll
      for (int j = 0; j < 4; ++j) {
        acc[i][j] = MFMA_BF16(ah[i], bh[j], acc[i][j]);
        acc[i][j] = MFMA_BF16(al[i], bh[j], acc[i][j]);
        acc[i][j] = MFMA_BF16(ah[i], bl[j], acc[i][j]);
      }
    __syncthreads();
  }

#pragma unroll
  for (int i = 0; i < 4; ++i) {
#pragma unroll
    for (int r = 0; r < 4; ++r) {
      int c = c0 + wr * 64 + i * 16 + lk * 4 + r;
      if (c >= PROJ_ROWS) continue;
      float bia = biasall[c];
      bool do_silu = (c < 512) || (c >= 608 && c < 612);
      bool do_sig  = (c >= 512 && c < 576) || (c == 612);
#pragma unroll
      for (int j = 0; j < 4; ++j) {
        float z = acc[i][j][r] + bia;
        if (do_silu) z = siluf_(z);
        else if (do_sig) z = sigmoidf_(z);
        projT[(size_t)c * PTOT + p0 + wc * 64 + j * 16 + lm] = z;
      }
    }
  }
}

// ---------------------------------------------------------------------------
// Iteration kernel v3: one block per (n-pair, r, batch), 12 iterations fused.
// Threads own 3x3 pixel strips (16x16 grid of strips = 48x48): conv reads a
// 5x5 neighborhood (25 LDS reads) per 9 outputs instead of 81.
// Output Hg is written f32 in [k][p] layout: each block owns 2 complete rows
// -> full-line L2 writebacks (fixes the 8x cross-block write amplification).
// ---------------------------------------------------------------------------
__global__ __launch_bounds__(256) void iter_kernel(
    const float* __restrict__ projT, const float* __restrict__ conv_w,
    const float* __restrict__ conv_b, float* __restrict__ HgF) {
  const int n2 = blockIdx.x;   // channel pair 0..31
  const int r  = blockIdx.y;   // 0..3
  const int b  = blockIdx.z;   // 0..15
  const int n0 = 2 * n2, n1 = n0 + 1;
  const int tid = threadIdx.x;
  const int bh = tid >> 4, bw = tid & 15;   // 3x3 strip coords
  const int pbase = b * IMG;

  __shared__ float2 HS[2][50 * 51];   // [buf][(h+1)*51 + (w+1)], zero halo

  // wave-uniform conv weights -> SGPRs
  float w0[9], w1[9];
#pragma unroll
  for (int t = 0; t < 9; ++t) {
    w0[t] = rfl(conv_w[t * 64 + n0]);
    w1[t] = rfl(conv_w[t * 64 + n1]);
  }
  const float cvb0 = rfl(conv_b[n0]), cvb1 = rfl(conv_b[n1]);

  // zero both buffers (2*2550 float2 = 2550 float4)
  {
    float4 zz = {0.f, 0.f, 0.f, 0.f};
    float4* z = (float4*)&HS[0][0];
#pragma unroll
    for (int u = 0; u < 10; ++u) {
      int q = tid + 256 * u;
      if (q < 2550) z[q] = zz;
    }
  }

  const float* rowB0 = projT + (size_t)(n0 * 4 + r) * PTOT + pbase;
  const float* rowB1 = projT + (size_t)(n1 * 4 + r) * PTOT + pbase;
  const float* rowC0 = projT + (size_t)(256 + n0 * 4 + r) * PTOT + pbase;
  const float* rowC1 = projT + (size_t)(256 + n1 * 4 + r) * PTOT + pbase;
  const float* rowA0 = projT + (size_t)(512 + n0) * PTOT + pbase;
  const float* rowA1 = projT + (size_t)(512 + n1) * PTOT + pbase;
  const float* rowTh = projT + (size_t)(576 + n2) * PTOT + pbase;
  const float* rowXv = projT + (size_t)(608 + r) * PTOT + pbase;
  const float* rowGm = projT + (size_t)612 * PTOT + pbase;

  float be0[9], be1[9], cb[9], sb[9], al0[9], al1[9], gmv[9];
#pragma unroll
  for (int s = 0; s < 9; ++s) {
    int dy = s / 3, dx = s - 3 * dy;
    int i = (3 * bh + dy) * 48 + 3 * bw + dx;
    float sn, cn;
    __sincosf(rowTh[i], &sn, &cn);
    cb[s] = cn; sb[s] = sn;
    float B0 = rowB0[i], B1 = rowB1[i], X = rowXv[i];
    be0[s] = (B0 * cn - B1 * sn) * X;   // inj at angle theta (iteration 0)
    be1[s] = (B0 * sn + B1 * cn) * X;
    al0[s] = rowA0[i]; al1[s] = rowA1[i];
    gmv[s] = rowGm[i];
  }
  __syncthreads();

  int cur = 0;
  for (int it = 0; it < 12; ++it) {
    float a0[9], a1[9];
#pragma unroll
    for (int s = 0; s < 9; ++s) { a0[s] = cvb0; a1[s] = cvb1; }
    // conv over 5x5 neighborhood, accumulate by tap-row (5 float2 live)
#pragma unroll
    for (int yy = 0; yy < 5; ++yy) {
      float2 row[5];
#pragma unroll
      for (int xx = 0; xx < 5; ++xx)
        row[xx] = HS[cur][(3 * bh + yy) * 51 + 3 * bw + xx];
#pragma unroll
      for (int dy = 0; dy < 3; ++dy) {
        int ty = yy - dy;
        if (ty < 0 || ty > 2) continue;
#pragma unroll
        for (int dx = 0; dx < 3; ++dx)
#pragma unroll
          for (int tx = 0; tx < 3; ++tx) {
            a0[dy * 3 + dx] += row[dx + tx].x * w0[ty * 3 + tx];
            a1[dy * 3 + dx] += row[dx + tx].y * w1[ty * 3 + tx];
          }
      }
    }
    // state update + write next buffer
#pragma unroll
    for (int s = 0; s < 9; ++s) {
      int dy = s / 3, dx = s - 3 * dy;
      float h0, h1;
      if (it == 0) {
        h0 = al0[s] * a0[s] + be0[s];
        h1 = al1[s] * a1[s] + be1[s];
      } else {
        // prev inj = rot(beta, -theta)
        float p0 = be0[s] * cb[s] + be1[s] * sb[s];
        float p1 = be1[s] * cb[s] - be0[s] * sb[s];
        float g = gmv[s];
        h0 = al0[s] * (a0[s] + (1.f - g) * p0) + g * be0[s];
        h1 = al1[s] * (a1[s] + (1.f - g) * p1) + g * be1[s];
      }
      float2 hw; hw.x = h0; hw.y = h1;
      HS[cur ^ 1][(3 * bh + dy + 1) * 51 + (3 * bw + dx + 1)] = hw;
      if (it < 11) {                   // advance beta by theta
        float nb0 = be0[s] * cb[s] - be1[s] * sb[s];
        float nb1 = be0[s] * sb[s] + be1[s] * cb[s];
        be0[s] = nb0; be1[s] = nb1;
      }
    }
    __syncthreads();
    cur ^= 1;
  }

  // Hg = rope(C, 12*theta) * Hst -> f32, [k][p] layout (k = r*64 + n)
  float* outRow0 = HgF + (size_t)(r * 64 + n0) * PTOT + pbase;
  float* outRow1 = HgF + (size_t)(r * 64 + n1) * PTOT + pbase;
#pragma unroll
  for (int s = 0; s < 9; ++s) {
    int dy = s / 3, dx = s - 3 * dy;
    int i = (3 * bh + dy) * 48 + 3 * bw + dx;
    // (cb + i sb)^12 via complex squarings
    float c2 = cb[s] * cb[s] - sb[s] * sb[s], s2 = 2.f * cb[s] * sb[s];
    float c4 = c2 * c2 - s2 * s2,             s4 = 2.f * c2 * s2;
    float c8 = c4 * c4 - s4 * s4,             s8 = 2.f * c4 * s4;
    float c12 = c8 * c4 - s8 * s4,            s12 = c8 * s4 + s8 * c4;
    float C0 = rowC0[i], C1 = rowC1[i];
    float cr0 = C0 * c12 - C1 * s12;
    float cr1 = C0 * s12 + C1 * c12;
    float2 hv = HS[cur][(3 * bh + dy + 1) * 51 + (3 * bw + dx + 1)];
    outRow0[i] = cr0 * hv.x;
    outRow1[i] = cr1 * hv.y;
  }
}

// ---------------------------------------------------------------------------
// transpose+split: HgF [k][p] f32 -> Hhi/Hlo [p][k] bf16 (64x64 LDS tiles).
// Both global sides coalesced; per-block output chunks are full cache lines.
// ---------------------------------------------------------------------------
__global__ __launch_bounds__(256) void transpose_split(
    const float* __restrict__ HgF, ushort_t* __restrict__ Hhi,
    ushort_t* __restrict__ Hlo) {
  __shared__ float T[64][65];
  const int tid = threadIdx.x;
  const int p0 = blockIdx.x * 64;
  const int k0 = blockIdx.y * 64;
  {
    int row = tid >> 2, q = tid & 3;
    const float* src = &HgF[(size_t)(k0 + row) * PTOT + p0 + q * 16];
#pragma unroll
    for (int v = 0; v < 4; ++v) {
      float4 f = *(const float4*)(src + 4 * v);
      T[row][q * 16 + 4 * v + 0] = f.x;
      T[row][q * 16 + 4 * v + 1] = f.y;
      T[row][q * 16 + 4 * v + 2] = f.z;
      T[row][q * 16 + 4 * v + 3] = f.w;
    }
  }
  __syncthreads();
  {
    int pr = tid >> 2, kq = tid & 3;
    ushort_t h[16], l[16];
#pragma unroll
    for (int j = 0; j < 16; ++j) {
      float f = T[kq * 16 + j][pr];
      h[j] = bf16_rne(f);
      l[j] = bf16_rne(f - bf16_tof(h[j]));
    }
    size_t off = (size_t)(p0 + pr) * 256 + k0 + kq * 16;
    uint4 H0, H1, L0, L1;
    H0.x = (uint_t)h[0] | ((uint_t)h[1] << 16);  H0.y = (uint_t)h[2] | ((uint_t)h[3] << 16);
    H0.z = (uint_t)h[4] | ((uint_t)h[5] << 16);  H0.w = (uint_t)h[6] | ((uint_t)h[7] << 16);
    H1.x = (uint_t)h[8] | ((uint_t)h[9] << 16);  H1.y = (uint_t)h[10] | ((uint_t)h[11] << 16);
    H1.z = (uint_t)h[12] | ((uint_t)h[13] << 16); H1.w = (uint_t)h[14] | ((uint_t)h[15] << 16);
    L0.x = (uint_t)l[0] | ((uint_t)l[1] << 16);  L0.y = (uint_t)l[2] | ((uint_t)l[3] << 16);
    L0.z = (uint_t)l[4] | ((uint_t)l[5] << 16);  L0.w = (uint_t)l[6] | ((uint_t)l[7] << 16);
    L1.x = (uint_t)l[8] | ((uint_t)l[9] << 16);  L1.y = (uint_t)l[10] | ((uint_t)l[11] << 16);
    L1.z = (uint_t)l[12] | ((uint_t)l[13] << 16); L1.w = (uint_t)l[14] | ((uint_t)l[15] << 16);
    *(uint4*)&Hhi[off] = H0;
    *(uint4*)&Hhi[off + 8] = H1;
    *(uint4*)&Hlo[off] = L0;
    *(uint4*)&Hlo[off + 8] = L1;
  }
}

// ---------------------------------------------------------------------------
// GEMM C (split-bf16 MFMA): out[p][j] = silu( sum_k Hg[p][k]*W_out[k][j] + b )
// ---------------------------------------------------------------------------
__global__ __launch_bounds__(256) void gemm_out_mfma(
    const ushort_t* __restrict__ Hhi, const ushort_t* __restrict__ Hlo,
    const ushort_t* __restrict__ WoThi, const ushort_t* __restrict__ WoTlo,
    const float* __restrict__ b_out, float* __restrict__ out) {
  __shared__ ushort_t As_hi[4 * GSTR], As_lo[4 * GSTR];  // Hg tile
  __shared__ ushort_t Bs_hi[4 * GSTR], Bs_lo[4 * GSTR];  // W_out^T tile
  const int tid = threadIdx.x;
  int lin = blockIdx.y * 6 + blockIdx.x;          // 0..1727
  int id2 = (lin & 7) * 216 + (lin >> 3);
  const int jblk = id2 % 6, pblk = id2 / 6;
  const int j0 = jblk * 128, p0 = pblk * 128;
  const int lane = tid & 63, wv = tid >> 6;
  const int wr = wv >> 1, wc = wv & 1;
  const int lk = lane >> 4, lm = lane & 15;

  f32x4 acc[4][4];
#pragma unroll
  for (int i = 0; i < 4; ++i)
#pragma unroll
    for (int j = 0; j < 4; ++j) acc[i][j] = (f32x4)0.f;

  for (int k0 = 0; k0 < 256; k0 += 32) {
#pragma unroll
    for (int s = 0; s < 2; ++s) {
      int u = tid + 256 * s;
      int p = u >> 2, g = u & 3;
      size_t goff = (size_t)(p0 + p) * 256 + k0 + g * 8;
      *(uint4*)&As_hi[g * GSTR + p * 8] = *(const uint4*)&Hhi[goff];
      *(uint4*)&As_lo[g * GSTR + p * 8] = *(const uint4*)&Hlo[goff];
    }
#pragma unroll
    for (int s = 0; s < 2; ++s) {
      int u = tid + 256 * s;
      int j = u >> 2, g = u & 3;
      size_t goff = (size_t)(j0 + j) * 256 + k0 + g * 8;
      *(uint4*)&Bs_hi[g * GSTR + j * 8] = *(const uint4*)&WoThi[goff];
      *(uint4*)&Bs_lo[g * GSTR + j * 8] = *(const uint4*)&WoTlo[goff];
    }
    __syncthreads();
    bfx8 ah[4], al[4], bh[4], bl[4];
#pragma unroll
    for (int f = 0; f < 4; ++f) {
      int ai = lk * GSTR + (wr * 64 + f * 16 + lm) * 8;
      ah[f] = *(const bfx8*)&As_hi[ai];
      al[f] = *(const bfx8*)&As_lo[ai];
      int bi = lk * GSTR + (wc * 64 + f * 16 + lm) * 8;
      bh[f] = *(const bfx8*)&Bs_hi[bi];
      bl[f] = *(const bfx8*)&Bs_lo[bi];
    }
#pragma unroll
    for (int i = 0; i < 4; ++i)
#pragma unroll
      for (int j = 0; j < 4; ++j) {
        acc[i][j] = MFMA_BF16(ah[i], bh[j], acc[i][j]);
        acc[i][j] = MFMA_BF16(al[i], bh[j], acc[i][j]);
        acc[i][j] = MFMA_BF16(ah[i], bl[j], acc[i][j]);
      }
    __syncthreads();
  }

  float bo[4];
#pragma unroll
  for (int jj = 0; jj < 4; ++jj) bo[jj] = b_out[j0 + wc * 64 + jj * 16 + lm];
#pragma unroll
  for (int i = 0; i < 4; ++i) {
#pragma unroll
    for (int r = 0; r < 4; ++r) {
      int p = p0 + wr * 64 + i * 16 + lk * 4 + r;
      size_t rowoff = (size_t)p * DIM;
#pragma unroll
      for (int jj = 0; jj < 4; ++jj) {
        out[rowoff + j0 + wc * 64 + jj * 16 + lm] =
            siluf_(acc[i][jj][r] + bo[jj]);
      }
    }
  }
}

// ---------------------------------------------------------------------------
extern "C" void kernel_launch(void* const* d_in, const int* in_sizes, int n_in,
                              void* d_out, int out_size, void* d_ws, size_t ws_size,
                              hipStream_t stream) {
  const float* x      = (const float*)d_in[0];
  const float* W_B    = (const float*)d_in[1];
  const float* b_B    = (const float*)d_in[2];
  const float* W_C    = (const float*)d_in[3];
  const float* b_C    = (const float*)d_in[4];
  const float* W_X    = (const float*)d_in[5];
  const float* b_X    = (const float*)d_in[6];
  const float* W_dec  = (const float*)d_in[7];
  const float* b_dec  = (const float*)d_in[8];
  const float* W_th   = (const float*)d_in[9];
  const float* b_th   = (const float*)d_in[10];
  const float* W_lam  = (const float*)d_in[11];
  const float* b_lam  = (const float*)d_in[12];
  const float* B_bias = (const float*)d_in[13];
  const float* C_bias = (const float*)d_in[14];
  const float* conv_w = (const float*)d_in[15];
  const float* conv_b = (const float*)d_in[16];
  const float* W_out  = (const float*)d_in[17];
  const float* b_out  = (const float*)d_in[18];
  float* out = (float*)d_out;

  // workspace layout (~131.3 MB, same footprint as round 3):
  //  [weights ~2.75 MB][projT 90.8 MB][HgF 37.75 MB]
  //  Hhi/Hlo (37.7 MB) OVERLAY projT (dead after iter_kernel).
  ushort_t* WhiT  = (ushort_t*)d_ws;                      // 640*768
  ushort_t* WloT  = WhiT + (size_t)NCOLS * DIM;
  ushort_t* WoThi = WloT + (size_t)NCOLS * DIM;           // 768*256
  ushort_t* WoTlo = WoThi + (size_t)DIM * 256;
  float* bias_all = (float*)(WoTlo + (size_t)DIM * 256);  // 640
  float* projT    = bias_all + NCOLS;                     // 616*36864 f32
  float* HgF      = projT + (size_t)PROJ_ROWS * PTOT;     // 256*36864 f32
  ushort_t* Hhi   = (ushort_t*)projT;                     // overlay: 36864*256
  ushort_t* Hlo   = Hhi + (size_t)PTOT * 256;

  const int pack_elems = NCOLS * DIM + DIM * 256;
  pack_kernel<<<(pack_elems + 255) / 256, 256, 0, stream>>>(
      W_B, W_C, W_dec, W_th, W_X, W_lam,
      b_B, b_C, b_dec, b_th, b_X, b_lam, B_bias, C_bias, W_out,
      WhiT, WloT, WoThi, WoTlo, bias_all);

  gemm_proj_mfma<<<dim3(5, PTOT / 128), 256, 0, stream>>>(
      x, WhiT, WloT, bias_all, projT);

  iter_kernel<<<dim3(32, 4, 16), 256, 0, stream>>>(
      projT, conv_w, conv_b, HgF);

  transpose_split<<<dim3(PTOT / 64, 4), 256, 0, stream>>>(HgF, Hhi, Hlo);

  gemm_out_mfma<<<dim3(6, PTOT / 128), 256, 0, stream>>>(
      Hhi, Hlo, WoThi, WoTlo, b_out, out);
}